// Round 2
// baseline (1378.798 us; speedup 1.0000x reference)
//
#include <hip/hip_runtime.h>

// Talking-heads attention, fused two-phase flash-style implementation, v2.
// b=16, n=1024, dim=768, h=12, d=64.  Staged tensors fp16.
// S-MFMA/PV: 16x16x32 f16.  Head-mix (12x12) MFMAs: 16x16x16 f16.
//
// k_attn v2 redesign vs v1:
//  - scratch layout [j32][i16][slot16] (strides 324/20 halves) with granule
//    XOR swizzle ((h>>2)^(i>>2)) -> packed b32+b16 S writes (~2-way banks),
//    aligned b64 fragment reads (~2-way), vs v1's 8-way scalar writes.
//  - softmax stats fully register-resident (lane owns (g,i) rows); single
//    cross-wave merge at end of phase 1. No shuffles.
//  - phase 1: double-buffered scratch, 1 barrier/tile. phase 2: 4/tile.
//  - LDS 49 KB -> 3 blocks/CU (launch_bounds(256,3)).

typedef _Float16 f16;
typedef _Float16 f16x2 __attribute__((ext_vector_type(2)));
typedef _Float16 f16x4 __attribute__((ext_vector_type(4)));
typedef _Float16 f16x8 __attribute__((ext_vector_type(8)));
typedef float f32x4 __attribute__((ext_vector_type(4)));
typedef float fv4 __attribute__((ext_vector_type(4)));

#define MFMA32(a, b, c) __builtin_amdgcn_mfma_f32_16x16x32_f16(a, b, c, 0, 0, 0)
#define MFMA16(a, b, c) __builtin_amdgcn_mfma_f32_16x16x16f16(a, b, c, 0, 0, 0)
#define EXP2(x) __builtin_amdgcn_exp2f(x)

// ---------------------------------------------------------------- cast x -> f16
__global__ __launch_bounds__(256) void k_cast_x(const float* __restrict__ x,
                                                f16* __restrict__ xb) {
  int idx = (blockIdx.x * 256 + threadIdx.x) * 8;
  fv4 a = *(const fv4*)(x + idx);
  fv4 b = *(const fv4*)(x + idx + 4);
  f16x8 o;
  o[0] = (f16)a[0]; o[1] = (f16)a[1]; o[2] = (f16)a[2]; o[3] = (f16)a[3];
  o[4] = (f16)b[0]; o[5] = (f16)b[1]; o[6] = (f16)b[2]; o[7] = (f16)b[3];
  *(f16x8*)(xb + idx) = o;
}

// ------------------------------------------- weights: transpose + cast (+scale q)
__global__ __launch_bounds__(256) void k_prep_w(const float* __restrict__ Wq,
                                                const float* __restrict__ Wkv,
                                                const float* __restrict__ Wo,
                                                f16* __restrict__ Wt,
                                                f16* __restrict__ WoT) {
  int idx = blockIdx.x * 256 + threadIdx.x;
  if (idx < 2304 * 768) {
    int n = idx / 768, k = idx % 768;
    float v = (n < 768) ? Wq[k * 768 + n] * 0.125f   // SCALE = 64^-0.5 folded here
                        : Wkv[k * 1536 + (n - 768)];
    Wt[idx] = (f16)v;
  } else {
    int id2 = idx - 2304 * 768;
    int n = id2 / 768, k = id2 % 768;
    WoT[id2] = (f16)Wo[k * 768 + n];
  }
}

// ---------------------------------------------------------------- QKV projection
__global__ __launch_bounds__(256) void k_gemm_qkv(const f16* __restrict__ A,
                                                  const f16* __restrict__ Bt,
                                                  f16* __restrict__ qb,
                                                  f16* __restrict__ kb,
                                                  f16* __restrict__ vb) {
  __shared__ f16 As[128 * 72];  // +8 pad: conflict-free b128 frag reads
  __shared__ f16 Bs[128 * 72];
  const int tid = threadIdx.x;
  const int m0 = blockIdx.y << 7;
  const int n0 = blockIdx.x << 7;
  const int lane = tid & 63, w = tid >> 6;
  const int quad = lane >> 4, col = lane & 15;
  const int wm = (w >> 1) << 6, wn = (w & 1) << 6;
  const f32x4 z4 = {0.f, 0.f, 0.f, 0.f};
  f32x4 acc[4][4];
#pragma unroll
  for (int i = 0; i < 4; ++i)
#pragma unroll
    for (int j = 0; j < 4; ++j) acc[i][j] = z4;

  for (int k0 = 0; k0 < 768; k0 += 64) {
#pragma unroll
    for (int s = 0; s < 4; ++s) {
      int u = s * 256 + tid;
      int row = u >> 3, seg = (u & 7) << 3;
      *(f16x8*)&As[row * 72 + seg] = *(const f16x8*)(A + (m0 + row) * 768 + k0 + seg);
      *(f16x8*)&Bs[row * 72 + seg] = *(const f16x8*)(Bt + (n0 + row) * 768 + k0 + seg);
    }
    __syncthreads();
#pragma unroll
    for (int kk = 0; kk < 64; kk += 32) {
      f16x8 af[4], bf[4];
#pragma unroll
      for (int ic = 0; ic < 4; ++ic)
        af[ic] = *(f16x8*)&As[(wm + ic * 16 + col) * 72 + kk + quad * 8];
#pragma unroll
      for (int jc = 0; jc < 4; ++jc)
        bf[jc] = *(f16x8*)&Bs[(wn + jc * 16 + col) * 72 + kk + quad * 8];
#pragma unroll
      for (int ic = 0; ic < 4; ++ic)
#pragma unroll
        for (int jc = 0; jc < 4; ++jc) acc[ic][jc] = MFMA32(af[ic], bf[jc], acc[ic][jc]);
    }
    __syncthreads();
  }
  // epilogue: scatter to per-head q/k/v layouts
#pragma unroll
  for (int jc = 0; jc < 4; ++jc) {
    int gn = n0 + wn + jc * 16 + col;
#pragma unroll
    for (int ic = 0; ic < 4; ++ic)
#pragma unroll
      for (int r = 0; r < 4; ++r) {
        int gm = m0 + wm + ic * 16 + (quad << 2) + r;
        int b = gm >> 10, i = gm & 1023;
        f16 v = (f16)acc[ic][jc][r];
        if (gn < 768) {
          int h = gn >> 6, dd = gn & 63;
          qb[(((b * 12 + h) << 10) + i) * 64 + dd] = v;
        } else if (gn < 1536) {
          int t = gn - 768; int h = t >> 6, dd = t & 63;
          kb[(((b * 12 + h) << 10) + i) * 64 + dd] = v;
        } else {
          int t = gn - 1536; int h = t >> 6, dd = t & 63;
          vb[(((b * 12 + h) << 10) + i) * 64 + dd] = v;
        }
      }
  }
}

// ---------------------------------------------------------------- V transpose
__global__ __launch_bounds__(256) void k_transpose_v(const f16* __restrict__ vb,
                                                     f16* __restrict__ vt) {
  __shared__ f16 t[64 * 72];
  const int bh = blockIdx.x;        // 0..191
  const int n0 = blockIdx.y << 6;   // 16 tiles of 64
  const int tid = threadIdx.x;
#pragma unroll
  for (int s = 0; s < 2; ++s) {
    int u = s * 256 + tid;
    int r = u >> 3, c = (u & 7) << 3;
    *(f16x8*)&t[r * 72 + c] = *(const f16x8*)(vb + (bh * 1024 + n0 + r) * 64 + c);
  }
  __syncthreads();
#pragma unroll
  for (int s = 0; s < 2; ++s) {
    int u = s * 256 + tid;
    int d = u >> 3, c = (u & 7) << 3;
    f16x8 o;
#pragma unroll
    for (int e = 0; e < 8; ++e) o[e] = t[(c + e) * 72 + d];
    *(f16x8*)(vt + (bh * 64 + d) * 1024 + n0 + c) = o;
  }
}

// ---------------------------------------------------------------- fused attention
// 256 thr (4 waves) per (b, 16 query rows).  j-tile 32.
// S compute: h-split (wave w owns heads 3w..3w+2).  Mix/softmax: j-split
// (wave w owns j columns 8w..8w+7 of the tile).  PV: g'-split (3 heads/wave).
// Scratch layout [j][i][slot]: strides j=324, i=20 halves; slot granule (4
// halves) XOR-swizzled with (i>>2) so writes and b64 reads are ~2-way banked.
__global__ __launch_bounds__(256, 3) void k_attn(
    const f16* __restrict__ qb, const f16* __restrict__ kb, const f16* __restrict__ vt,
    const float* __restrict__ mixp, const float* __restrict__ mixq,
    f16* __restrict__ ob) {
  __shared__ f16 SA[10368];     // S scratch (phase1 dbuf A; phase2 S + Pm region)
  __shared__ f16 SB[10368];     // S scratch (phase1 dbuf B; phase2 P')
  __shared__ float msL[1024];   // [w][g16][i16] partial m
  __shared__ float lsL[1024];   // [w][g16][i16] partial l

  const int tid = threadIdx.x;
  const int bid = blockIdx.x;
  const int b  = bid >> 6;
  const int i0 = (bid & 63) << 4;
  const int lane = tid & 63;
  const int w = tid >> 6;
  const int quad = lane >> 4, col = lane & 15;
  const int q4 = quad << 2;
  const int w3 = w * 3;
  const int sp0   = (w & 1) ? 1 : 0;    // s-index of even-h pair low
  const int soloS = (w & 1) ? 0 : 2;
  const int pairH = w3 + sp0;           // even
  const int soloH = w3 + soloS;
  const f32x4 z4 = {0.f, 0.f, 0.f, 0.f};

  // zero scratch: slot positions >=12 must be finite (0) -- MFMA pad lanes
  // multiply them by zero coefficients, and 0 * Inf/NaN would poison results.
  {
    f16x8 z8 = {};
    for (int z = tid; z < 1296; z += 256) ((f16x8*)SA)[z] = z8;
    for (int z = tid; z < 1296; z += 256) ((f16x8*)SB)[z] = z8;
  }

  // mix fragments, 16x16x16 B-operand: lane holds B[k=quad*4+e][n=col]
  f16x4 b_pre, b_post;
#pragma unroll
  for (int e = 0; e < 4; ++e) {
    int k = q4 + e;
    bool ok = (k < 12) && (col < 12);
    b_pre[e]  = ok ? (f16)(mixp[k * 12 + col] * 1.44269504f) : (f16)0.f;  // log2e folded
    b_post[e] = ok ? (f16)(mixq[k * 12 + col]) : (f16)0.f;
  }

  // Q fragments (x32 A-operand: lane holds A[m=col][k=quad*8+e])
  f16x8 qf[3][2];
#pragma unroll
  for (int h3 = 0; h3 < 3; ++h3)
#pragma unroll
    for (int kc = 0; kc < 2; ++kc)
      qf[h3][kc] = *(const f16x8*)(qb + (((b * 12 + w3 + h3) << 10) + i0 + col) * 64 +
                                   kc * 32 + quad * 8);
  __syncthreads();  // zero-init visible

  const int granP = (((pairH >> 2) ^ quad) << 2) + (pairH & 3);
  const int granS = (((soloH >> 2) ^ quad) << 2) + (soloH & 3);
  const int mixOff = (quad ^ (col >> 2)) << 2;   // b64 read granule swizzle

  // computeS: wave's 3 heads, 32 j's -> scratch [j][i][h-slot]
  auto computeS = [&](int j0, f16* Sbuf) {
    f32x4 s[3][2];
#pragma unroll
    for (int h3 = 0; h3 < 3; ++h3) {
      const f16* kbase = kb + (((b * 12 + w3 + h3) << 10) + j0) * 64;
#pragma unroll
      for (int jn = 0; jn < 2; ++jn) {
        f32x4 acc = z4;
#pragma unroll
        for (int kc = 0; kc < 2; ++kc) {
          f16x8 kf = *(const f16x8*)(kbase + (jn * 16 + col) * 64 + kc * 32 + quad * 8);
          acc = MFMA32(qf[h3][kc], kf, acc);
        }
        s[h3][jn] = acc;
      }
    }
#pragma unroll
    for (int jn = 0; jn < 2; ++jn) {
      int base2 = (jn * 16 + col) * 324 + q4 * 20;
#pragma unroll
      for (int r = 0; r < 4; ++r) {
        int b2 = base2 + r * 20;
        f16x2 pk; pk[0] = (f16)s[sp0][jn][r]; pk[1] = (f16)s[sp0 + 1][jn][r];
        *(f16x2*)&Sbuf[b2 + granP] = pk;          // packed pair of heads
        Sbuf[b2 + granS] = (f16)s[soloS][jn][r];  // solo head
      }
    }
  };

  // ---------------- phase 1: stats.  lane owns rows (g=col, i=q4+r).
  float m_run[4], l_run[4];
#pragma unroll
  for (int r = 0; r < 4; ++r) { m_run[r] = -1e30f; l_run[r] = 0.f; }

  for (int t = 0; t < 32; ++t) {
    f16* Sbuf = (t & 1) ? SB : SA;
    computeS(t * 32, Sbuf);
    __syncthreads();
    f32x4 d1[8];
#pragma unroll
    for (int u = 0; u < 8; ++u) {
      f16x4 sf = *(f16x4*)&Sbuf[(w * 8 + u) * 324 + col * 20 + mixOff];
      d1[u] = MFMA16(sf, b_pre, z4);   // mixed logits * log2e; lane (col=g, row=i)
    }
#pragma unroll
    for (int r = 0; r < 4; ++r) {
      float mt = d1[0][r];
#pragma unroll
      for (int u = 1; u < 8; ++u) mt = fmaxf(mt, d1[u][r]);
      float mnew = fmaxf(m_run[r], mt);
      float se = 0.f;
#pragma unroll
      for (int u = 0; u < 8; ++u) se += EXP2(d1[u][r] - mnew);
      l_run[r] = l_run[r] * EXP2(m_run[r] - mnew) + se;
      m_run[r] = mnew;
    }
    // no trailing barrier: double-buffered scratch
  }

  // cross-wave (m,l) merge
#pragma unroll
  for (int r = 0; r < 4; ++r) {
    msL[w * 256 + col * 16 + q4 + r] = m_run[r];
    lsL[w * 256 + col * 16 + q4 + r] = l_run[r];
  }
  __syncthreads();
  float mv[4], il[4];
#pragma unroll
  for (int r = 0; r < 4; ++r) {
    int ix = col * 16 + q4 + r;
    float M = msL[ix];
    M = fmaxf(M, msL[256 + ix]);
    M = fmaxf(M, msL[512 + ix]);
    M = fmaxf(M, msL[768 + ix]);
    float L = 0.f;
#pragma unroll
    for (int wp = 0; wp < 4; ++wp)
      L += lsL[wp * 256 + ix] * EXP2(msL[wp * 256 + ix] - M);
    mv[r] = M; il[r] = 1.f / L;
  }

  // ---------------- phase 2: recompute S, P=softmax, mix_post, O += Pmix @ V
  f32x4 oa[3][4];
#pragma unroll
  for (int g3 = 0; g3 < 3; ++g3)
#pragma unroll
    for (int dc = 0; dc < 4; ++dc) oa[g3][dc] = z4;

  for (int t = 0; t < 32; ++t) {
    const int j0 = t * 32;
    computeS(j0, SA);
    __syncthreads();                        // S ready (also: prev PV reads done)
    // mix_pre + normalize -> P' in SB  [j][i][g-slot]
#pragma unroll
    for (int u = 0; u < 8; ++u) {
      int v = w * 8 + u;
      f16x4 sf = *(f16x4*)&SA[v * 324 + col * 20 + mixOff];
      f32x4 d1 = MFMA16(sf, b_pre, z4);
      if (col < 12) {
        int pbase = v * 324 + q4 * 20 + (((col >> 2) ^ quad) << 2) + (col & 3);
#pragma unroll
        for (int r = 0; r < 4; ++r)
          SB[pbase + r * 20] = (f16)(EXP2(d1[r] - mv[r]) * il[r]);
      }
    }
    __syncthreads();                        // P' ready (also: SA mix-reads done)
    // mix_post -> Pm region in SA  [g'][i][j32] (strides 648/40, j-gran swizzle)
#pragma unroll
    for (int u = 0; u < 8; ++u) {
      int v = w * 8 + u;
      f16x4 pf = *(f16x4*)&SB[v * 324 + col * 20 + mixOff];
      f32x4 d2 = MFMA16(pf, b_post, z4);
      if (col < 12) {
#pragma unroll
        for (int r = 0; r < 4; ++r)
          SA[col * 648 + (q4 + r) * 40 + ((w ^ r) << 3) + u] = (f16)d2[r];
      }
    }
    __syncthreads();                        // Pm ready
    // PV: wave w accumulates output heads 3w..3w+2
#pragma unroll
    for (int g3 = 0; g3 < 3; ++g3) {
      int gp = w3 + g3;
      f16x8 af = *(f16x8*)&SA[gp * 648 + col * 40 + ((quad ^ (col & 3)) << 3)];
#pragma unroll
      for (int dc = 0; dc < 4; ++dc) {
        f16x8 vf = *(const f16x8*)(vt + (((b * 12 + gp) * 64 + dc * 16 + col) << 10) +
                                   j0 + quad * 8);
        oa[g3][dc] = MFMA32(af, vf, oa[g3][dc]);
      }
    }
    __syncthreads();                        // PV done; SA free for next tile
  }

  // epilogue: O (row=q4+r = i, col = d) -> obuf [b][n][768]
#pragma unroll
  for (int g3 = 0; g3 < 3; ++g3) {
    int gp = w3 + g3;
#pragma unroll
    for (int dc = 0; dc < 4; ++dc)
#pragma unroll
      for (int r = 0; r < 4; ++r)
        ob[((b << 10) + i0 + q4 + r) * 768 + gp * 64 + dc * 16 + col] =
            (f16)oa[g3][dc][r];
  }
}

// ---------------------------------------------------------------- output GEMM
__global__ __launch_bounds__(256) void k_gemm_out(const f16* __restrict__ A,
                                                  const f16* __restrict__ Bt,
                                                  const float* __restrict__ bias,
                                                  float* __restrict__ out) {
  __shared__ f16 As[128 * 72];
  __shared__ f16 Bs[128 * 72];
  const int tid = threadIdx.x;
  const int m0 = blockIdx.y << 7;
  const int n0 = blockIdx.x << 7;
  const int lane = tid & 63, w = tid >> 6;
  const int quad = lane >> 4, col = lane & 15;
  const int wm = (w >> 1) << 6, wn = (w & 1) << 6;
  const f32x4 z4 = {0.f, 0.f, 0.f, 0.f};
  f32x4 acc[4][4];
#pragma unroll
  for (int i = 0; i < 4; ++i)
#pragma unroll
    for (int j = 0; j < 4; ++j) acc[i][j] = z4;

  for (int k0 = 0; k0 < 768; k0 += 64) {
#pragma unroll
    for (int s = 0; s < 4; ++s) {
      int u = s * 256 + tid;
      int row = u >> 3, seg = (u & 7) << 3;
      *(f16x8*)&As[row * 72 + seg] = *(const f16x8*)(A + (m0 + row) * 768 + k0 + seg);
      *(f16x8*)&Bs[row * 72 + seg] = *(const f16x8*)(Bt + (n0 + row) * 768 + k0 + seg);
    }
    __syncthreads();
#pragma unroll
    for (int kk = 0; kk < 64; kk += 32) {
      f16x8 af[4], bf[4];
#pragma unroll
      for (int ic = 0; ic < 4; ++ic)
        af[ic] = *(f16x8*)&As[(wm + ic * 16 + col) * 72 + kk + quad * 8];
#pragma unroll
      for (int jc = 0; jc < 4; ++jc)
        bf[jc] = *(f16x8*)&Bs[(wn + jc * 16 + col) * 72 + kk + quad * 8];
#pragma unroll
      for (int ic = 0; ic < 4; ++ic)
#pragma unroll
        for (int jc = 0; jc < 4; ++jc) acc[ic][jc] = MFMA32(af[ic], bf[jc], acc[ic][jc]);
    }
    __syncthreads();
  }
#pragma unroll
  for (int jc = 0; jc < 4; ++jc) {
    int gn = n0 + wn + jc * 16 + col;
    float bv = bias[gn];
#pragma unroll
    for (int ic = 0; ic < 4; ++ic)
#pragma unroll
      for (int r = 0; r < 4; ++r) {
        int gm = m0 + wm + ic * 16 + (quad << 2) + r;
        out[gm * 768 + gn] = acc[ic][jc][r] + bv;
      }
  }
}

// ---------------------------------------------------------------- launcher
extern "C" void kernel_launch(void* const* d_in, const int* in_sizes, int n_in,
                              void* d_out, int out_size, void* d_ws, size_t ws_size,
                              hipStream_t stream) {
  const float* x    = (const float*)d_in[0];
  const float* Wq   = (const float*)d_in[1];
  const float* Wkv  = (const float*)d_in[2];
  const float* mixp = (const float*)d_in[3];
  const float* mixq = (const float*)d_in[4];
  const float* Wo   = (const float*)d_in[5];
  const float* bo   = (const float*)d_in[6];
  float* out = (float*)d_out;

  char* ws = (char*)d_ws;
  f16* xb  = (f16*)(ws);
  f16* Wt  = (f16*)(ws + 25165824);
  f16* WoT = (f16*)(ws + 28704768);
  f16* qb  = (f16*)(ws + 29884416);
  f16* kb  = (f16*)(ws + 55050240);
  f16* vb  = (f16*)(ws + 80216064);
  f16* vt  = xb;   // xb dead after k_gemm_qkv
  f16* obuf = vb;  // vb dead after k_transpose_v

  k_cast_x<<<dim3(6144), dim3(256), 0, stream>>>(x, xb);
  k_prep_w<<<dim3(9216), dim3(256), 0, stream>>>(Wq, Wkv, Wo, Wt, WoT);
  k_gemm_qkv<<<dim3(18, 128), dim3(256), 0, stream>>>(xb, Wt, qb, kb, vb);
  k_transpose_v<<<dim3(192, 16), dim3(256), 0, stream>>>(vb, vt);
  k_attn<<<dim3(1024), dim3(256), 0, stream>>>(qb, kb, vt, mixp, mixq, obuf);
  k_gemm_out<<<dim3(6, 128), dim3(256), 0, stream>>>(obuf, WoT, bo, out);
}

// Round 3
// 957.557 us; speedup vs baseline: 1.4399x; 1.4399x over previous
//
#include <hip/hip_runtime.h>

// Talking-heads attention, fused two-phase flash-style implementation, v3.
// b=16, n=1024, dim=768, h=12, d=64.  Staged tensors fp16.
// S-MFMA/PV: 16x16x32 f16.  Head-mix (12x12) MFMAs: 16x16x16 f16.
//
// v3 = v2 with the scratch-spill bug fixed: v2 indexed the S accumulator
// register array with runtime values (s[sp0][jn]) -> LLVM spilled it to
// scratch memory -> +270 MB HBM traffic, VALUBusy 50%, 2x regression.
// v3 keeps all register-array indices compile-time; head pairing for the
// packed f16x2 store is a wave-uniform branch on (w&1), both sides static.

typedef _Float16 f16;
typedef _Float16 f16x2 __attribute__((ext_vector_type(2)));
typedef _Float16 f16x4 __attribute__((ext_vector_type(4)));
typedef _Float16 f16x8 __attribute__((ext_vector_type(8)));
typedef float f32x4 __attribute__((ext_vector_type(4)));
typedef float fv4 __attribute__((ext_vector_type(4)));

#define MFMA32(a, b, c) __builtin_amdgcn_mfma_f32_16x16x32_f16(a, b, c, 0, 0, 0)
#define MFMA16(a, b, c) __builtin_amdgcn_mfma_f32_16x16x16f16(a, b, c, 0, 0, 0)
#define EXP2(x) __builtin_amdgcn_exp2f(x)

// ---------------------------------------------------------------- cast x -> f16
__global__ __launch_bounds__(256) void k_cast_x(const float* __restrict__ x,
                                                f16* __restrict__ xb) {
  int idx = (blockIdx.x * 256 + threadIdx.x) * 8;
  fv4 a = *(const fv4*)(x + idx);
  fv4 b = *(const fv4*)(x + idx + 4);
  f16x8 o;
  o[0] = (f16)a[0]; o[1] = (f16)a[1]; o[2] = (f16)a[2]; o[3] = (f16)a[3];
  o[4] = (f16)b[0]; o[5] = (f16)b[1]; o[6] = (f16)b[2]; o[7] = (f16)b[3];
  *(f16x8*)(xb + idx) = o;
}

// ------------------------------------------- weights: transpose + cast (+scale q)
__global__ __launch_bounds__(256) void k_prep_w(const float* __restrict__ Wq,
                                                const float* __restrict__ Wkv,
                                                const float* __restrict__ Wo,
                                                f16* __restrict__ Wt,
                                                f16* __restrict__ WoT) {
  int idx = blockIdx.x * 256 + threadIdx.x;
  if (idx < 2304 * 768) {
    int n = idx / 768, k = idx % 768;
    float v = (n < 768) ? Wq[k * 768 + n] * 0.125f   // SCALE = 64^-0.5 folded here
                        : Wkv[k * 1536 + (n - 768)];
    Wt[idx] = (f16)v;
  } else {
    int id2 = idx - 2304 * 768;
    int n = id2 / 768, k = id2 % 768;
    WoT[id2] = (f16)Wo[k * 768 + n];
  }
}

// ---------------------------------------------------------------- QKV projection
__global__ __launch_bounds__(256) void k_gemm_qkv(const f16* __restrict__ A,
                                                  const f16* __restrict__ Bt,
                                                  f16* __restrict__ qb,
                                                  f16* __restrict__ kb,
                                                  f16* __restrict__ vb) {
  __shared__ f16 As[128 * 72];  // +8 pad: conflict-free b128 frag reads
  __shared__ f16 Bs[128 * 72];
  const int tid = threadIdx.x;
  const int m0 = blockIdx.y << 7;
  const int n0 = blockIdx.x << 7;
  const int lane = tid & 63, w = tid >> 6;
  const int quad = lane >> 4, col = lane & 15;
  const int wm = (w >> 1) << 6, wn = (w & 1) << 6;
  const f32x4 z4 = {0.f, 0.f, 0.f, 0.f};
  f32x4 acc[4][4];
#pragma unroll
  for (int i = 0; i < 4; ++i)
#pragma unroll
    for (int j = 0; j < 4; ++j) acc[i][j] = z4;

  for (int k0 = 0; k0 < 768; k0 += 64) {
#pragma unroll
    for (int s = 0; s < 4; ++s) {
      int u = s * 256 + tid;
      int row = u >> 3, seg = (u & 7) << 3;
      *(f16x8*)&As[row * 72 + seg] = *(const f16x8*)(A + (m0 + row) * 768 + k0 + seg);
      *(f16x8*)&Bs[row * 72 + seg] = *(const f16x8*)(Bt + (n0 + row) * 768 + k0 + seg);
    }
    __syncthreads();
#pragma unroll
    for (int kk = 0; kk < 64; kk += 32) {
      f16x8 af[4], bf[4];
#pragma unroll
      for (int ic = 0; ic < 4; ++ic)
        af[ic] = *(f16x8*)&As[(wm + ic * 16 + col) * 72 + kk + quad * 8];
#pragma unroll
      for (int jc = 0; jc < 4; ++jc)
        bf[jc] = *(f16x8*)&Bs[(wn + jc * 16 + col) * 72 + kk + quad * 8];
#pragma unroll
      for (int ic = 0; ic < 4; ++ic)
#pragma unroll
        for (int jc = 0; jc < 4; ++jc) acc[ic][jc] = MFMA32(af[ic], bf[jc], acc[ic][jc]);
    }
    __syncthreads();
  }
  // epilogue: scatter to per-head q/k/v layouts
#pragma unroll
  for (int jc = 0; jc < 4; ++jc) {
    int gn = n0 + wn + jc * 16 + col;
#pragma unroll
    for (int ic = 0; ic < 4; ++ic)
#pragma unroll
      for (int r = 0; r < 4; ++r) {
        int gm = m0 + wm + ic * 16 + (quad << 2) + r;
        int b = gm >> 10, i = gm & 1023;
        f16 v = (f16)acc[ic][jc][r];
        if (gn < 768) {
          int h = gn >> 6, dd = gn & 63;
          qb[(((b * 12 + h) << 10) + i) * 64 + dd] = v;
        } else if (gn < 1536) {
          int t = gn - 768; int h = t >> 6, dd = t & 63;
          kb[(((b * 12 + h) << 10) + i) * 64 + dd] = v;
        } else {
          int t = gn - 1536; int h = t >> 6, dd = t & 63;
          vb[(((b * 12 + h) << 10) + i) * 64 + dd] = v;
        }
      }
  }
}

// ---------------------------------------------------------------- V transpose
__global__ __launch_bounds__(256) void k_transpose_v(const f16* __restrict__ vb,
                                                     f16* __restrict__ vt) {
  __shared__ f16 t[64 * 72];
  const int bh = blockIdx.x;        // 0..191
  const int n0 = blockIdx.y << 6;   // 16 tiles of 64
  const int tid = threadIdx.x;
#pragma unroll
  for (int s = 0; s < 2; ++s) {
    int u = s * 256 + tid;
    int r = u >> 3, c = (u & 7) << 3;
    *(f16x8*)&t[r * 72 + c] = *(const f16x8*)(vb + (bh * 1024 + n0 + r) * 64 + c);
  }
  __syncthreads();
#pragma unroll
  for (int s = 0; s < 2; ++s) {
    int u = s * 256 + tid;
    int d = u >> 3, c = (u & 7) << 3;
    f16x8 o;
#pragma unroll
    for (int e = 0; e < 8; ++e) o[e] = t[(c + e) * 72 + d];
    *(f16x8*)(vt + (bh * 64 + d) * 1024 + n0 + c) = o;
  }
}

// ---------------------------------------------------------------- fused attention
// 256 thr (4 waves) per (b, 16 query rows).  j-tile 32.
// S compute: h-split (wave w owns heads 3w..3w+2).  Mix/softmax: j-split
// (wave w owns j columns 8w..8w+7 of the tile).  PV: g'-split (3 heads/wave).
// Scratch layout [j][i][slot]: strides j=324, i=20 halves; slot granule (4
// halves) XOR-swizzled with (i>>2) so writes and b64 reads are ~2-way banked.
// ALL register-array indices are compile-time (see v3 note at top).
__global__ __launch_bounds__(256, 3) void k_attn(
    const f16* __restrict__ qb, const f16* __restrict__ kb, const f16* __restrict__ vt,
    const float* __restrict__ mixp, const float* __restrict__ mixq,
    f16* __restrict__ ob) {
  __shared__ f16 SA[10368];     // S scratch (phase1 dbuf A; phase2 S + Pm region)
  __shared__ f16 SB[10368];     // S scratch (phase1 dbuf B; phase2 P')
  __shared__ float msL[1024];   // [w][g16][i16] partial m
  __shared__ float lsL[1024];   // [w][g16][i16] partial l

  const int tid = threadIdx.x;
  const int bid = blockIdx.x;
  const int b  = bid >> 6;
  const int i0 = (bid & 63) << 4;
  const int lane = tid & 63;
  const int w = tid >> 6;
  const int quad = lane >> 4, col = lane & 15;
  const int q4 = quad << 2;
  const int w3 = w * 3;
  // head pairing (static within each branch below): even w pairs (s0,s1) solo s2;
  // odd w pairs (s1,s2) solo s0.  granP/granS are just address values.
  const int pairH = w3 + (w & 1);       // even head of the adjacent pair
  const int soloH = (w & 1) ? w3 : w3 + 2;
  const f32x4 z4 = {0.f, 0.f, 0.f, 0.f};

  // zero scratch: slot positions >=12 must be finite (0) -- MFMA pad lanes
  // multiply them by zero coefficients, and 0 * Inf/NaN would poison results.
  {
    f16x8 z8 = {};
    for (int z = tid; z < 1296; z += 256) ((f16x8*)SA)[z] = z8;
    for (int z = tid; z < 1296; z += 256) ((f16x8*)SB)[z] = z8;
  }

  // mix fragments, 16x16x16 B-operand: lane holds B[k=quad*4+e][n=col]
  f16x4 b_pre, b_post;
#pragma unroll
  for (int e = 0; e < 4; ++e) {
    int k = q4 + e;
    bool ok = (k < 12) && (col < 12);
    b_pre[e]  = ok ? (f16)(mixp[k * 12 + col] * 1.44269504f) : (f16)0.f;  // log2e folded
    b_post[e] = ok ? (f16)(mixq[k * 12 + col]) : (f16)0.f;
  }

  // Q fragments (x32 A-operand: lane holds A[m=col][k=quad*8+e])
  f16x8 qf[3][2];
#pragma unroll
  for (int h3 = 0; h3 < 3; ++h3)
#pragma unroll
    for (int kc = 0; kc < 2; ++kc)
      qf[h3][kc] = *(const f16x8*)(qb + (((b * 12 + w3 + h3) << 10) + i0 + col) * 64 +
                                   kc * 32 + quad * 8);
  __syncthreads();  // zero-init visible

  const int granP = (((pairH >> 2) ^ quad) << 2) + (pairH & 3);
  const int granS = (((soloH >> 2) ^ quad) << 2) + (soloH & 3);
  const int mixOff = (quad ^ (col >> 2)) << 2;   // b64 read granule swizzle

  // computeS: wave's 3 heads, 32 j's -> scratch [j][i][h-slot]
  auto computeS = [&](int j0, f16* Sbuf) {
    f32x4 s[3][2];
#pragma unroll
    for (int h3 = 0; h3 < 3; ++h3) {
      const f16* kbase = kb + (((b * 12 + w3 + h3) << 10) + j0) * 64;
#pragma unroll
      for (int jn = 0; jn < 2; ++jn) {
        f32x4 acc = z4;
#pragma unroll
        for (int kc = 0; kc < 2; ++kc) {
          f16x8 kf = *(const f16x8*)(kbase + (jn * 16 + col) * 64 + kc * 32 + quad * 8);
          acc = MFMA32(qf[h3][kc], kf, acc);
        }
        s[h3][jn] = acc;
      }
    }
    // store: all s[] indices are literals in both wave-uniform branches
    if ((w & 1) == 0) {
#pragma unroll
      for (int jn = 0; jn < 2; ++jn) {
        int base2 = (jn * 16 + col) * 324 + q4 * 20;
#pragma unroll
        for (int r = 0; r < 4; ++r) {
          int b2 = base2 + r * 20;
          f16x2 pk; pk[0] = (f16)s[0][jn][r]; pk[1] = (f16)s[1][jn][r];
          *(f16x2*)&Sbuf[b2 + granP] = pk;
          Sbuf[b2 + granS] = (f16)s[2][jn][r];
        }
      }
    } else {
#pragma unroll
      for (int jn = 0; jn < 2; ++jn) {
        int base2 = (jn * 16 + col) * 324 + q4 * 20;
#pragma unroll
        for (int r = 0; r < 4; ++r) {
          int b2 = base2 + r * 20;
          f16x2 pk; pk[0] = (f16)s[1][jn][r]; pk[1] = (f16)s[2][jn][r];
          *(f16x2*)&Sbuf[b2 + granP] = pk;
          Sbuf[b2 + granS] = (f16)s[0][jn][r];
        }
      }
    }
  };

  // ---------------- phase 1: stats.  lane owns rows (g=col, i=q4+r).
  float m_run[4], l_run[4];
#pragma unroll
  for (int r = 0; r < 4; ++r) { m_run[r] = -1e30f; l_run[r] = 0.f; }

  for (int t = 0; t < 32; ++t) {
    f16* Sbuf = (t & 1) ? SB : SA;
    computeS(t * 32, Sbuf);
    __syncthreads();
    f32x4 d1[8];
#pragma unroll
    for (int u = 0; u < 8; ++u) {
      f16x4 sf = *(f16x4*)&Sbuf[(w * 8 + u) * 324 + col * 20 + mixOff];
      d1[u] = MFMA16(sf, b_pre, z4);   // mixed logits * log2e; lane (col=g, row=i)
    }
#pragma unroll
    for (int r = 0; r < 4; ++r) {
      float mt = d1[0][r];
#pragma unroll
      for (int u = 1; u < 8; ++u) mt = fmaxf(mt, d1[u][r]);
      float mnew = fmaxf(m_run[r], mt);
      float se = 0.f;
#pragma unroll
      for (int u = 0; u < 8; ++u) se += EXP2(d1[u][r] - mnew);
      l_run[r] = l_run[r] * EXP2(m_run[r] - mnew) + se;
      m_run[r] = mnew;
    }
    // no trailing barrier: double-buffered scratch
  }

  // cross-wave (m,l) merge
#pragma unroll
  for (int r = 0; r < 4; ++r) {
    msL[w * 256 + col * 16 + q4 + r] = m_run[r];
    lsL[w * 256 + col * 16 + q4 + r] = l_run[r];
  }
  __syncthreads();
  float mv[4], il[4];
#pragma unroll
  for (int r = 0; r < 4; ++r) {
    int ix = col * 16 + q4 + r;
    float M = msL[ix];
    M = fmaxf(M, msL[256 + ix]);
    M = fmaxf(M, msL[512 + ix]);
    M = fmaxf(M, msL[768 + ix]);
    float L = 0.f;
#pragma unroll
    for (int wp = 0; wp < 4; ++wp)
      L += lsL[wp * 256 + ix] * EXP2(msL[wp * 256 + ix] - M);
    mv[r] = M; il[r] = 1.f / L;
  }

  // ---------------- phase 2: recompute S, P=softmax, mix_post, O += Pmix @ V
  f32x4 oa[3][4];
#pragma unroll
  for (int g3 = 0; g3 < 3; ++g3)
#pragma unroll
    for (int dc = 0; dc < 4; ++dc) oa[g3][dc] = z4;

  for (int t = 0; t < 32; ++t) {
    const int j0 = t * 32;
    computeS(j0, SA);
    __syncthreads();                        // S ready (also: prev PV reads done)
    // mix_pre + normalize -> P' in SB  [j][i][g-slot]
#pragma unroll
    for (int u = 0; u < 8; ++u) {
      int v = w * 8 + u;
      f16x4 sf = *(f16x4*)&SA[v * 324 + col * 20 + mixOff];
      f32x4 d1 = MFMA16(sf, b_pre, z4);
      if (col < 12) {
        int pbase = v * 324 + q4 * 20 + (((col >> 2) ^ quad) << 2) + (col & 3);
#pragma unroll
        for (int r = 0; r < 4; ++r)
          SB[pbase + r * 20] = (f16)(EXP2(d1[r] - mv[r]) * il[r]);
      }
    }
    __syncthreads();                        // P' ready (also: SA mix-reads done)
    // mix_post -> Pm region in SA  [g'][i][j32] (strides 648/40, j-gran swizzle)
#pragma unroll
    for (int u = 0; u < 8; ++u) {
      int v = w * 8 + u;
      f16x4 pf = *(f16x4*)&SB[v * 324 + col * 20 + mixOff];
      f32x4 d2 = MFMA16(pf, b_post, z4);
      if (col < 12) {
#pragma unroll
        for (int r = 0; r < 4; ++r)
          SA[col * 648 + (q4 + r) * 40 + ((w ^ r) << 3) + u] = (f16)d2[r];
      }
    }
    __syncthreads();                        // Pm ready
    // PV: wave w accumulates output heads 3w..3w+2
#pragma unroll
    for (int g3 = 0; g3 < 3; ++g3) {
      int gp = w3 + g3;
      f16x8 af = *(f16x8*)&SA[gp * 648 + col * 40 + ((quad ^ (col & 3)) << 3)];
#pragma unroll
      for (int dc = 0; dc < 4; ++dc) {
        f16x8 vf = *(const f16x8*)(vt + (((b * 12 + gp) * 64 + dc * 16 + col) << 10) +
                                   j0 + quad * 8);
        oa[g3][dc] = MFMA32(af, vf, oa[g3][dc]);
      }
    }
    __syncthreads();                        // PV done; SA free for next tile
  }

  // epilogue: O (row=q4+r = i, col = d) -> obuf [b][n][768]
#pragma unroll
  for (int g3 = 0; g3 < 3; ++g3) {
    int gp = w3 + g3;
#pragma unroll
    for (int dc = 0; dc < 4; ++dc)
#pragma unroll
      for (int r = 0; r < 4; ++r)
        ob[((b << 10) + i0 + q4 + r) * 768 + gp * 64 + dc * 16 + col] =
            (f16)oa[g3][dc][r];
  }
}

// ---------------------------------------------------------------- output GEMM
__global__ __launch_bounds__(256) void k_gemm_out(const f16* __restrict__ A,
                                                  const f16* __restrict__ Bt,
                                                  const float* __restrict__ bias,
                                                  float* __restrict__ out) {
  __shared__ f16 As[128 * 72];
  __shared__ f16 Bs[128 * 72];
  const int tid = threadIdx.x;
  const int m0 = blockIdx.y << 7;
  const int n0 = blockIdx.x << 7;
  const int lane = tid & 63, w = tid >> 6;
  const int quad = lane >> 4, col = lane & 15;
  const int wm = (w >> 1) << 6, wn = (w & 1) << 6;
  const f32x4 z4 = {0.f, 0.f, 0.f, 0.f};
  f32x4 acc[4][4];
#pragma unroll
  for (int i = 0; i < 4; ++i)
#pragma unroll
    for (int j = 0; j < 4; ++j) acc[i][j] = z4;

  for (int k0 = 0; k0 < 768; k0 += 64) {
#pragma unroll
    for (int s = 0; s < 4; ++s) {
      int u = s * 256 + tid;
      int row = u >> 3, seg = (u & 7) << 3;
      *(f16x8*)&As[row * 72 + seg] = *(const f16x8*)(A + (m0 + row) * 768 + k0 + seg);
      *(f16x8*)&Bs[row * 72 + seg] = *(const f16x8*)(Bt + (n0 + row) * 768 + k0 + seg);
    }
    __syncthreads();
#pragma unroll
    for (int kk = 0; kk < 64; kk += 32) {
      f16x8 af[4], bf[4];
#pragma unroll
      for (int ic = 0; ic < 4; ++ic)
        af[ic] = *(f16x8*)&As[(wm + ic * 16 + col) * 72 + kk + quad * 8];
#pragma unroll
      for (int jc = 0; jc < 4; ++jc)
        bf[jc] = *(f16x8*)&Bs[(wn + jc * 16 + col) * 72 + kk + quad * 8];
#pragma unroll
      for (int ic = 0; ic < 4; ++ic)
#pragma unroll
        for (int jc = 0; jc < 4; ++jc) acc[ic][jc] = MFMA32(af[ic], bf[jc], acc[ic][jc]);
    }
    __syncthreads();
  }
#pragma unroll
  for (int jc = 0; jc < 4; ++jc) {
    int gn = n0 + wn + jc * 16 + col;
    float bv = bias[gn];
#pragma unroll
    for (int ic = 0; ic < 4; ++ic)
#pragma unroll
      for (int r = 0; r < 4; ++r) {
        int gm = m0 + wm + ic * 16 + (quad << 2) + r;
        out[gm * 768 + gn] = acc[ic][jc][r] + bv;
      }
  }
}

// ---------------------------------------------------------------- launcher
extern "C" void kernel_launch(void* const* d_in, const int* in_sizes, int n_in,
                              void* d_out, int out_size, void* d_ws, size_t ws_size,
                              hipStream_t stream) {
  const float* x    = (const float*)d_in[0];
  const float* Wq   = (const float*)d_in[1];
  const float* Wkv  = (const float*)d_in[2];
  const float* mixp = (const float*)d_in[3];
  const float* mixq = (const float*)d_in[4];
  const float* Wo   = (const float*)d_in[5];
  const float* bo   = (const float*)d_in[6];
  float* out = (float*)d_out;

  char* ws = (char*)d_ws;
  f16* xb  = (f16*)(ws);
  f16* Wt  = (f16*)(ws + 25165824);
  f16* WoT = (f16*)(ws + 28704768);
  f16* qb  = (f16*)(ws + 29884416);
  f16* kb  = (f16*)(ws + 55050240);
  f16* vb  = (f16*)(ws + 80216064);
  f16* vt  = xb;   // xb dead after k_gemm_qkv
  f16* obuf = vb;  // vb dead after k_transpose_v

  k_cast_x<<<dim3(6144), dim3(256), 0, stream>>>(x, xb);
  k_prep_w<<<dim3(9216), dim3(256), 0, stream>>>(Wq, Wkv, Wo, Wt, WoT);
  k_gemm_qkv<<<dim3(18, 128), dim3(256), 0, stream>>>(xb, Wt, qb, kb, vb);
  k_transpose_v<<<dim3(192, 16), dim3(256), 0, stream>>>(vb, vt);
  k_attn<<<dim3(1024), dim3(256), 0, stream>>>(qb, kb, vt, mixp, mixq, obuf);
  k_gemm_out<<<dim3(6, 128), dim3(256), 0, stream>>>(obuf, WoT, bo, out);
}

// Round 4
// 910.327 us; speedup vs baseline: 1.5146x; 1.0519x over previous
//
#include <hip/hip_runtime.h>

// Talking-heads attention, fused two-phase flash-style implementation, v4.
// b=16, n=1024, dim=768, h=12, d=64.  Staged tensors fp16.
// S-MFMA/PV: 16x16x32 f16.  Head-mix (12x12) MFMAs: 16x16x16 f16.
//
// v4 vs v3: operand-swapped mixes.  MFMA16(mix^T as A, S as B) puts the mix
// output in [g][i-lane] layout, which IS the B-operand layout of the next
// mix MFMA -> mix_pre -> exp -> mix_post chains entirely in registers (P'
// LDS round trip deleted).  Phase 2: 2 barriers/tile, PV(t-1) overlaps
// computeS(t).  Stats keys (g=q4+r, i=col) register-resident through both
// phases.  LDS 36.7 KB (msL/lsL overlay the Pm region) -> 4 blocks/CU.

typedef _Float16 f16;
typedef _Float16 f16x2 __attribute__((ext_vector_type(2)));
typedef _Float16 f16x4 __attribute__((ext_vector_type(4)));
typedef _Float16 f16x8 __attribute__((ext_vector_type(8)));
typedef float f32x4 __attribute__((ext_vector_type(4)));
typedef float fv4 __attribute__((ext_vector_type(4)));

#define MFMA32(a, b, c) __builtin_amdgcn_mfma_f32_16x16x32_f16(a, b, c, 0, 0, 0)
#define MFMA16(a, b, c) __builtin_amdgcn_mfma_f32_16x16x16f16(a, b, c, 0, 0, 0)
#define EXP2(x) __builtin_amdgcn_exp2f(x)

// ---------------------------------------------------------------- cast x -> f16
__global__ __launch_bounds__(256) void k_cast_x(const float* __restrict__ x,
                                                f16* __restrict__ xb) {
  int idx = (blockIdx.x * 256 + threadIdx.x) * 8;
  fv4 a = *(const fv4*)(x + idx);
  fv4 b = *(const fv4*)(x + idx + 4);
  f16x8 o;
  o[0] = (f16)a[0]; o[1] = (f16)a[1]; o[2] = (f16)a[2]; o[3] = (f16)a[3];
  o[4] = (f16)b[0]; o[5] = (f16)b[1]; o[6] = (f16)b[2]; o[7] = (f16)b[3];
  *(f16x8*)(xb + idx) = o;
}

// ------------------------------------------- weights: transpose + cast (+scale q)
__global__ __launch_bounds__(256) void k_prep_w(const float* __restrict__ Wq,
                                                const float* __restrict__ Wkv,
                                                const float* __restrict__ Wo,
                                                f16* __restrict__ Wt,
                                                f16* __restrict__ WoT) {
  int idx = blockIdx.x * 256 + threadIdx.x;
  if (idx < 2304 * 768) {
    int n = idx / 768, k = idx % 768;
    float v = (n < 768) ? Wq[k * 768 + n] * 0.125f   // SCALE = 64^-0.5 folded here
                        : Wkv[k * 1536 + (n - 768)];
    Wt[idx] = (f16)v;
  } else {
    int id2 = idx - 2304 * 768;
    int n = id2 / 768, k = id2 % 768;
    WoT[id2] = (f16)Wo[k * 768 + n];
  }
}

// ---------------------------------------------------------------- QKV projection
__global__ __launch_bounds__(256) void k_gemm_qkv(const f16* __restrict__ A,
                                                  const f16* __restrict__ Bt,
                                                  f16* __restrict__ qb,
                                                  f16* __restrict__ kb,
                                                  f16* __restrict__ vb) {
  __shared__ f16 As[128 * 72];  // +8 pad: conflict-free b128 frag reads
  __shared__ f16 Bs[128 * 72];
  const int tid = threadIdx.x;
  const int m0 = blockIdx.y << 7;
  const int n0 = blockIdx.x << 7;
  const int lane = tid & 63, w = tid >> 6;
  const int quad = lane >> 4, col = lane & 15;
  const int wm = (w >> 1) << 6, wn = (w & 1) << 6;
  const f32x4 z4 = {0.f, 0.f, 0.f, 0.f};
  f32x4 acc[4][4];
#pragma unroll
  for (int i = 0; i < 4; ++i)
#pragma unroll
    for (int j = 0; j < 4; ++j) acc[i][j] = z4;

  for (int k0 = 0; k0 < 768; k0 += 64) {
#pragma unroll
    for (int s = 0; s < 4; ++s) {
      int u = s * 256 + tid;
      int row = u >> 3, seg = (u & 7) << 3;
      *(f16x8*)&As[row * 72 + seg] = *(const f16x8*)(A + (m0 + row) * 768 + k0 + seg);
      *(f16x8*)&Bs[row * 72 + seg] = *(const f16x8*)(Bt + (n0 + row) * 768 + k0 + seg);
    }
    __syncthreads();
#pragma unroll
    for (int kk = 0; kk < 64; kk += 32) {
      f16x8 af[4], bf[4];
#pragma unroll
      for (int ic = 0; ic < 4; ++ic)
        af[ic] = *(f16x8*)&As[(wm + ic * 16 + col) * 72 + kk + quad * 8];
#pragma unroll
      for (int jc = 0; jc < 4; ++jc)
        bf[jc] = *(f16x8*)&Bs[(wn + jc * 16 + col) * 72 + kk + quad * 8];
#pragma unroll
      for (int ic = 0; ic < 4; ++ic)
#pragma unroll
        for (int jc = 0; jc < 4; ++jc) acc[ic][jc] = MFMA32(af[ic], bf[jc], acc[ic][jc]);
    }
    __syncthreads();
  }
  // epilogue: scatter to per-head q/k/v layouts
#pragma unroll
  for (int jc = 0; jc < 4; ++jc) {
    int gn = n0 + wn + jc * 16 + col;
#pragma unroll
    for (int ic = 0; ic < 4; ++ic)
#pragma unroll
      for (int r = 0; r < 4; ++r) {
        int gm = m0 + wm + ic * 16 + (quad << 2) + r;
        int b = gm >> 10, i = gm & 1023;
        f16 v = (f16)acc[ic][jc][r];
        if (gn < 768) {
          int h = gn >> 6, dd = gn & 63;
          qb[(((b * 12 + h) << 10) + i) * 64 + dd] = v;
        } else if (gn < 1536) {
          int t = gn - 768; int h = t >> 6, dd = t & 63;
          kb[(((b * 12 + h) << 10) + i) * 64 + dd] = v;
        } else {
          int t = gn - 1536; int h = t >> 6, dd = t & 63;
          vb[(((b * 12 + h) << 10) + i) * 64 + dd] = v;
        }
      }
  }
}

// ---------------------------------------------------------------- V transpose
__global__ __launch_bounds__(256) void k_transpose_v(const f16* __restrict__ vb,
                                                     f16* __restrict__ vt) {
  __shared__ f16 t[64 * 72];
  const int bh = blockIdx.x;        // 0..191
  const int n0 = blockIdx.y << 6;   // 16 tiles of 64
  const int tid = threadIdx.x;
#pragma unroll
  for (int s = 0; s < 2; ++s) {
    int u = s * 256 + tid;
    int r = u >> 3, c = (u & 7) << 3;
    *(f16x8*)&t[r * 72 + c] = *(const f16x8*)(vb + (bh * 1024 + n0 + r) * 64 + c);
  }
  __syncthreads();
#pragma unroll
  for (int s = 0; s < 2; ++s) {
    int u = s * 256 + tid;
    int d = u >> 3, c = (u & 7) << 3;
    f16x8 o;
#pragma unroll
    for (int e = 0; e < 8; ++e) o[e] = t[(c + e) * 72 + d];
    *(f16x8*)(vt + (bh * 64 + d) * 1024 + n0 + c) = o;
  }
}

// ---------------------------------------------------------------- fused attention
// 256 thr (4 waves) per (b, 16 query rows).  j-tile 32.
// S compute: h-split (wave w owns heads 3w..3w+2) into SA [j][i][h-slot]
// (strides 324/20, granule swizzle ((h>>2)^(i>>2)), v3-proven).
// Mix chain per j-chunk: B-frag read of S^T -> MFMA16(a_pre, sf) ->
// d1[g=q4+r][i=col] -> exp (register) -> MFMA16(a_post, pb) -> d2[g'][i]
// -> Pm[g'][i][j] in LDS -> PV.  Stats (m,l) register-resident at
// (g=q4+r, i=col).  Phase 1: 2 barriers/tile (single buffer).
// Phase 2: 2 barriers/tile, PV(t-1) overlaps computeS(t).
__global__ __launch_bounds__(256, 4) void k_attn(
    const f16* __restrict__ qb, const f16* __restrict__ kb, const f16* __restrict__ vt,
    const float* __restrict__ mixp, const float* __restrict__ mixq,
    f16* __restrict__ ob) {
  __shared__ f16 SA[10368];     // S scratch [j32][i16][slot], strides 324/20
  __shared__ f16 PmB[7968];     // Pm [g'12][i16][j32], strides 664/40, gran swizzle
                                //  (phase-1 merge overlays msL/lsL here)
  float* msL = (float*)PmB;          // [w][g16][i16]
  float* lsL = (float*)(PmB + 2048); // [w][g16][i16]

  const int tid = threadIdx.x;
  const int bid = blockIdx.x;
  const int b  = bid >> 6;
  const int i0 = (bid & 63) << 4;
  const int lane = tid & 63;
  const int w = tid >> 6;
  const int quad = lane >> 4, col = lane & 15;
  const int q4 = quad << 2;
  const int w3 = w * 3, w8 = w * 8;
  const int pairH = w3 + (w & 1);            // even head of the adjacent pair
  const int soloH = (w & 1) ? w3 : w3 + 2;
  const f32x4 z4 = {0.f, 0.f, 0.f, 0.f};

  // zero SA: pad h-slots (>=12) must stay finite 0 forever (0 x NaN guard)
  {
    f16x8 z8 = {};
    for (int z = tid; z < 1296; z += 256) ((f16x8*)SA)[z] = z8;
  }

  // mix fragments.  Same per-lane values as a B-operand of M serve as the
  // A-operand of M^T: A[m=col][k=q4+e] = M[k][col].  log2e folded into pre.
  f16x4 a_pre, a_post;
#pragma unroll
  for (int e = 0; e < 4; ++e) {
    int k = q4 + e;
    bool ok = (k < 12) && (col < 12);
    a_pre[e]  = ok ? (f16)(mixp[k * 12 + col] * 1.44269504f) : (f16)0.f;
    a_post[e] = ok ? (f16)(mixq[k * 12 + col]) : (f16)0.f;
  }

  // Q fragments (x32 A-operand: lane holds A[m=col][k=quad*8+e])
  f16x8 qf[3][2];
#pragma unroll
  for (int h3 = 0; h3 < 3; ++h3)
#pragma unroll
    for (int kc = 0; kc < 2; ++kc)
      qf[h3][kc] = *(const f16x8*)(qb + (((b * 12 + w3 + h3) << 10) + i0 + col) * 64 +
                                   kc * 32 + quad * 8);

  const int granP = (((pairH >> 2) ^ quad) << 2) + (pairH & 3);
  const int granS = (((soloH >> 2) ^ quad) << 2) + (soloH & 3);
  const int mixOff = (quad ^ (col >> 2)) << 2;   // S b64 read granule swizzle
  const int pmWr = col * 40 + (((w ^ (col & 3))) << 3);    // Pm store base
  const int pmRd = col * 40 + (((quad ^ (col & 3))) << 3); // Pm read base

  // computeS: wave's 3 heads, 32 j's -> SA [j][i][h-slot]
  auto computeS = [&](int j0) {
    f32x4 s[3][2];
#pragma unroll
    for (int h3 = 0; h3 < 3; ++h3) {
      const f16* kbase = kb + (((b * 12 + w3 + h3) << 10) + j0) * 64;
#pragma unroll
      for (int jn = 0; jn < 2; ++jn) {
        f32x4 acc = z4;
#pragma unroll
        for (int kc = 0; kc < 2; ++kc) {
          f16x8 kf = *(const f16x8*)(kbase + (jn * 16 + col) * 64 + kc * 32 + quad * 8);
          acc = MFMA32(qf[h3][kc], kf, acc);
        }
        s[h3][jn] = acc;
      }
    }
    if ((w & 1) == 0) {   // all s[] indices literal in both uniform branches
#pragma unroll
      for (int jn = 0; jn < 2; ++jn) {
        int base2 = (jn * 16 + col) * 324 + q4 * 20;
#pragma unroll
        for (int r = 0; r < 4; ++r) {
          int b2 = base2 + r * 20;
          f16x2 pk; pk[0] = (f16)s[0][jn][r]; pk[1] = (f16)s[1][jn][r];
          *(f16x2*)&SA[b2 + granP] = pk;
          SA[b2 + granS] = (f16)s[2][jn][r];
        }
      }
    } else {
#pragma unroll
      for (int jn = 0; jn < 2; ++jn) {
        int base2 = (jn * 16 + col) * 324 + q4 * 20;
#pragma unroll
        for (int r = 0; r < 4; ++r) {
          int b2 = base2 + r * 20;
          f16x2 pk; pk[0] = (f16)s[1][jn][r]; pk[1] = (f16)s[2][jn][r];
          *(f16x2*)&SA[b2 + granP] = pk;
          SA[b2 + granS] = (f16)s[0][jn][r];
        }
      }
    }
  };

  // ---------------- phase 1: stats.  lane owns (g=q4+r, i=col).
  float m_run[4], l_run[4];
#pragma unroll
  for (int r = 0; r < 4; ++r) { m_run[r] = -1e30f; l_run[r] = 0.f; }

  for (int t = 0; t < 32; ++t) {
    computeS(t * 32);
    __syncthreads();                 // S ready (t=0: also zero-init visible)
    f32x4 d1[8];
#pragma unroll
    for (int u = 0; u < 8; ++u) {
      f16x4 sf = *(f16x4*)&SA[(w8 + u) * 324 + col * 20 + mixOff];
      d1[u] = MFMA16(a_pre, sf, z4);   // [g=q4+r][i=col], log2-domain
    }
#pragma unroll
    for (int r = 0; r < 4; ++r) {
      float mt = d1[0][r];
#pragma unroll
      for (int u = 1; u < 8; ++u) mt = fmaxf(mt, d1[u][r]);
      float mnew = fmaxf(m_run[r], mt);
      float se = 0.f;
#pragma unroll
      for (int u = 0; u < 8; ++u) se += EXP2(d1[u][r] - mnew);
      l_run[r] = l_run[r] * EXP2(m_run[r] - mnew) + se;
      m_run[r] = mnew;
    }
    if (t < 31) __syncthreads();     // reads done before next S write
  }

  // cross-wave merge (msL/lsL overlay PmB; SA untouched, pad zeros live on)
#pragma unroll
  for (int r = 0; r < 4; ++r) {
    msL[w * 256 + (q4 + r) * 16 + col] = m_run[r];
    lsL[w * 256 + (q4 + r) * 16 + col] = l_run[r];
  }
  __syncthreads();
  float mv[4], il[4];
#pragma unroll
  for (int r = 0; r < 4; ++r) {
    int ix = (q4 + r) * 16 + col;
    float M = msL[ix];
    M = fmaxf(M, msL[256 + ix]);
    M = fmaxf(M, msL[512 + ix]);
    M = fmaxf(M, msL[768 + ix]);
    float L = 0.f;
#pragma unroll
    for (int wp = 0; wp < 4; ++wp)
      L += lsL[wp * 256 + ix] * EXP2(msL[wp * 256 + ix] - M);
    mv[r] = M; il[r] = 1.f / L;
  }
  __syncthreads();                   // merge reads done; PmB free for Pm

  // ---------------- phase 2: S -> mix chain in regs -> Pm -> PV
  f32x4 oa[3][4];
#pragma unroll
  for (int g3 = 0; g3 < 3; ++g3)
#pragma unroll
    for (int dc = 0; dc < 4; ++dc) oa[g3][dc] = z4;

  for (int t = 0; t < 32; ++t) {
    computeS(t * 32);                // writes SA (Pm reads below hit PmB)
    if (t > 0) {
      const int jp = (t - 1) * 32;   // PV(t-1) overlaps computeS(t)
#pragma unroll
      for (int g3 = 0; g3 < 3; ++g3) {
        int gp = w3 + g3;
        f16x8 af = *(f16x8*)&PmB[gp * 664 + pmRd];
#pragma unroll
        for (int dc = 0; dc < 4; ++dc) {
          f16x8 vf = *(const f16x8*)(vt + (((b * 12 + gp) * 64 + dc * 16 + col) << 10) +
                                     jp + quad * 8);
          oa[g3][dc] = MFMA32(af, vf, oa[g3][dc]);
        }
      }
    }
    __syncthreads();                 // S ready; Pm(t-1) reads done
    // mix chain: S^T frag -> mix_pre -> exp (registers) -> mix_post -> Pm
#pragma unroll
    for (int u = 0; u < 8; ++u) {
      f16x4 sf = *(f16x4*)&SA[(w8 + u) * 324 + col * 20 + mixOff];
      f32x4 d1 = MFMA16(a_pre, sf, z4);
      f16x4 pb;
#pragma unroll
      for (int e = 0; e < 4; ++e)
        pb[e] = (f16)(EXP2(d1[e] - mv[e]) * il[e]);
      f32x4 d2 = MFMA16(a_post, pb, z4);   // [g'=q4+r][i=col]
      if (quad < 3) {
#pragma unroll
        for (int r = 0; r < 4; ++r)
          PmB[(q4 + r) * 664 + pmWr + u] = (f16)d2[r];
      }
    }
    __syncthreads();                 // Pm ready; SA reads done
  }
  // final PV tile
  {
    const int jp = 31 * 32;
#pragma unroll
    for (int g3 = 0; g3 < 3; ++g3) {
      int gp = w3 + g3;
      f16x8 af = *(f16x8*)&PmB[gp * 664 + pmRd];
#pragma unroll
      for (int dc = 0; dc < 4; ++dc) {
        f16x8 vf = *(const f16x8*)(vt + (((b * 12 + gp) * 64 + dc * 16 + col) << 10) +
                                   jp + quad * 8);
        oa[g3][dc] = MFMA32(af, vf, oa[g3][dc]);
      }
    }
  }

  // epilogue: O (row=q4+r = i, col = d) -> obuf [b][n][768]
#pragma unroll
  for (int g3 = 0; g3 < 3; ++g3) {
    int gp = w3 + g3;
#pragma unroll
    for (int dc = 0; dc < 4; ++dc)
#pragma unroll
      for (int r = 0; r < 4; ++r)
        ob[((b << 10) + i0 + q4 + r) * 768 + gp * 64 + dc * 16 + col] =
            (f16)oa[g3][dc][r];
  }
}

// ---------------------------------------------------------------- output GEMM
__global__ __launch_bounds__(256) void k_gemm_out(const f16* __restrict__ A,
                                                  const f16* __restrict__ Bt,
                                                  const float* __restrict__ bias,
                                                  float* __restrict__ out) {
  __shared__ f16 As[128 * 72];
  __shared__ f16 Bs[128 * 72];
  const int tid = threadIdx.x;
  const int m0 = blockIdx.y << 7;
  const int n0 = blockIdx.x << 7;
  const int lane = tid & 63, w = tid >> 6;
  const int quad = lane >> 4, col = lane & 15;
  const int wm = (w >> 1) << 6, wn = (w & 1) << 6;
  const f32x4 z4 = {0.f, 0.f, 0.f, 0.f};
  f32x4 acc[4][4];
#pragma unroll
  for (int i = 0; i < 4; ++i)
#pragma unroll
    for (int j = 0; j < 4; ++j) acc[i][j] = z4;

  for (int k0 = 0; k0 < 768; k0 += 64) {
#pragma unroll
    for (int s = 0; s < 4; ++s) {
      int u = s * 256 + tid;
      int row = u >> 3, seg = (u & 7) << 3;
      *(f16x8*)&As[row * 72 + seg] = *(const f16x8*)(A + (m0 + row) * 768 + k0 + seg);
      *(f16x8*)&Bs[row * 72 + seg] = *(const f16x8*)(Bt + (n0 + row) * 768 + k0 + seg);
    }
    __syncthreads();
#pragma unroll
    for (int kk = 0; kk < 64; kk += 32) {
      f16x8 af[4], bf[4];
#pragma unroll
      for (int ic = 0; ic < 4; ++ic)
        af[ic] = *(f16x8*)&As[(wm + ic * 16 + col) * 72 + kk + quad * 8];
#pragma unroll
      for (int jc = 0; jc < 4; ++jc)
        bf[jc] = *(f16x8*)&Bs[(wn + jc * 16 + col) * 72 + kk + quad * 8];
#pragma unroll
      for (int ic = 0; ic < 4; ++ic)
#pragma unroll
        for (int jc = 0; jc < 4; ++jc) acc[ic][jc] = MFMA32(af[ic], bf[jc], acc[ic][jc]);
    }
    __syncthreads();
  }
#pragma unroll
  for (int jc = 0; jc < 4; ++jc) {
    int gn = n0 + wn + jc * 16 + col;
    float bv = bias[gn];
#pragma unroll
    for (int ic = 0; ic < 4; ++ic)
#pragma unroll
      for (int r = 0; r < 4; ++r) {
        int gm = m0 + wm + ic * 16 + (quad << 2) + r;
        out[gm * 768 + gn] = acc[ic][jc][r] + bv;
      }
  }
}

// ---------------------------------------------------------------- launcher
extern "C" void kernel_launch(void* const* d_in, const int* in_sizes, int n_in,
                              void* d_out, int out_size, void* d_ws, size_t ws_size,
                              hipStream_t stream) {
  const float* x    = (const float*)d_in[0];
  const float* Wq   = (const float*)d_in[1];
  const float* Wkv  = (const float*)d_in[2];
  const float* mixp = (const float*)d_in[3];
  const float* mixq = (const float*)d_in[4];
  const float* Wo   = (const float*)d_in[5];
  const float* bo   = (const float*)d_in[6];
  float* out = (float*)d_out;

  char* ws = (char*)d_ws;
  f16* xb  = (f16*)(ws);
  f16* Wt  = (f16*)(ws + 25165824);
  f16* WoT = (f16*)(ws + 28704768);
  f16* qb  = (f16*)(ws + 29884416);
  f16* kb  = (f16*)(ws + 55050240);
  f16* vb  = (f16*)(ws + 80216064);
  f16* vt  = xb;   // xb dead after k_gemm_qkv
  f16* obuf = vb;  // vb dead after k_transpose_v

  k_cast_x<<<dim3(6144), dim3(256), 0, stream>>>(x, xb);
  k_prep_w<<<dim3(9216), dim3(256), 0, stream>>>(Wq, Wkv, Wo, Wt, WoT);
  k_gemm_qkv<<<dim3(18, 128), dim3(256), 0, stream>>>(xb, Wt, qb, kb, vb);
  k_transpose_v<<<dim3(192, 16), dim3(256), 0, stream>>>(vb, vt);
  k_attn<<<dim3(1024), dim3(256), 0, stream>>>(qb, kb, vt, mixp, mixq, obuf);
  k_gemm_out<<<dim3(6, 128), dim3(256), 0, stream>>>(obuf, WoT, bo, out);
}